// Round 7
// baseline (257.455 us; speedup 1.0000x reference)
//
#include <hip/hip_runtime.h>
#include <hip/hip_fp16.h>

#define NN     100000
#define NE     1600000
#define FEAT   128
#define HID    64
#define OUTD   40
#define BSH    7                         // bucket = dst >> 7 (128 nodes/bucket)
#define BNODES 128
#define NBKT   ((NN + BNODES - 1) / BNODES)   // 782
#define CAP    2560                      // bucket capacity (mean 2048, sd ~45)
#define CCHUNK 6144                      // edges per block in pair-scatter (mult of 4)

typedef _Float16 half8 __attribute__((ext_vector_type(8)));
typedef float    f32x4 __attribute__((ext_vector_type(4)));

// ---- A. scatter packed (src<<7|dl) into padded bucket segments ----
__global__ __launch_bounds__(256) void k_pairs(const int* __restrict__ src,
                                               const int* __restrict__ dst,
                                               int* __restrict__ bfill,
                                               int* __restrict__ pairs) {
    __shared__ int bcnt[NBKT];
    __shared__ int gb[NBKT];
    for (int i = threadIdx.x; i < NBKT; i += 256) bcnt[i] = 0;
    __syncthreads();
    int e0 = blockIdx.x * CCHUNK;
    int e1 = min(NE, e0 + CCHUNK);
    const int4* d4p = (const int4*)dst;
    const int4* s4p = (const int4*)src;
    for (int q = e0 / 4 + threadIdx.x; q < e1 / 4; q += 256) {
        int4 d4 = d4p[q];
        atomicAdd(&bcnt[d4.x >> BSH], 1);
        atomicAdd(&bcnt[d4.y >> BSH], 1);
        atomicAdd(&bcnt[d4.z >> BSH], 1);
        atomicAdd(&bcnt[d4.w >> BSH], 1);
    }
    __syncthreads();
    for (int i = threadIdx.x; i < NBKT; i += 256) {
        int c = bcnt[i];
        gb[i] = c ? (i * CAP + atomicAdd(&bfill[i], c)) : 0;
        bcnt[i] = 0;
    }
    __syncthreads();
    for (int q = e0 / 4 + threadIdx.x; q < e1 / 4; q += 256) {
        int4 d4 = d4p[q];
        int4 s4 = s4p[q];
        int b, idx;
        b = d4.x >> BSH; idx = gb[b] + atomicAdd(&bcnt[b], 1); pairs[idx] = (s4.x << BSH) | (d4.x & (BNODES-1));
        b = d4.y >> BSH; idx = gb[b] + atomicAdd(&bcnt[b], 1); pairs[idx] = (s4.y << BSH) | (d4.y & (BNODES-1));
        b = d4.z >> BSH; idx = gb[b] + atomicAdd(&bcnt[b], 1); pairs[idx] = (s4.z << BSH) | (d4.z & (BNODES-1));
        b = d4.w >> BSH; idx = gb[b] + atomicAdd(&bcnt[b], 1); pairs[idx] = (s4.w << BSH) | (d4.w & (BNODES-1));
    }
}

// ---- B. per-bucket degree hist -> global dinv ----
__global__ __launch_bounds__(256) void k_degdinv(const int* __restrict__ pairs,
                                                 const int* __restrict__ bfill,
                                                 float* __restrict__ dinv) {
    __shared__ int hist[BNODES];
    int b = blockIdx.x, t = threadIdx.x;
    if (t < BNODES) hist[t] = 0;
    __syncthreads();
    int base = b * CAP, count = bfill[b];
    for (int i = t; i < count; i += 256)
        atomicAdd(&hist[pairs[base + i] & (BNODES - 1)], 1);
    __syncthreads();
    int node = (b << BSH) + t;
    if (t < BNODES && node < NN) dinv[node] = rsqrtf((float)hist[t] + 1.0f);
}

// ---- C. pack W1/W2 into per-lane MFMA B-fragments (f16) ----
__global__ __launch_bounds__(256) void k_wprep(const float* __restrict__ W1,
                                               const float* __restrict__ W2,
                                               _Float16* __restrict__ w1f,
                                               _Float16* __restrict__ w2f) {
    int t = threadIdx.x;
    for (int it = t; it < 16 * 64; it += 256) {   // W1: kk 0..3 x n 0..3
        int f = it >> 6, l = it & 63;
        int kk = f >> 2, n = f & 3;
        int krow = kk * 32 + (l >> 4) * 8;
        int col  = n * 16 + (l & 15);
        #pragma unroll
        for (int i = 0; i < 8; ++i)
            w1f[it * 8 + i] = (_Float16)W1[(krow + i) * HID + col];
    }
    for (int it = t; it < 6 * 64; it += 256) {    // W2: kk 0..1 x n 0..2 (48-col pad)
        int f = it >> 6, l = it & 63;
        int kk = f / 3, n = f - kk * 3;
        int krow = kk * 32 + (l >> 4) * 8;
        int col  = n * 16 + (l & 15);
        #pragma unroll
        for (int i = 0; i < 8; ++i)
            w2f[it * 8 + i] = (col < OUTD) ? (_Float16)W2[(krow + i) * OUTD + col]
                                           : (_Float16)0.f;
    }
}

// ---- D. h1h = f16(x @ W1) via MFMA: wave = 16 rows x 64 cols ----
__global__ __launch_bounds__(256) void k_mgemm1(const float* __restrict__ x,
                                                const _Float16* __restrict__ w1f,
                                                __half* __restrict__ h1h) {
    int wid = (blockIdx.x * 256 + threadIdx.x) >> 6;
    int l = threadIdx.x & 63;
    if (wid >= NN / 16) return;
    half8 bf[4][4];
    #pragma unroll
    for (int kk = 0; kk < 4; ++kk)
        #pragma unroll
        for (int n = 0; n < 4; ++n)
            bf[kk][n] = ((const half8*)w1f)[(kk * 4 + n) * 64 + l];
    f32x4 acc[4] = {};
    int arow = wid * 16 + (l & 15);
    const float* xp = x + (size_t)arow * FEAT + (l >> 4) * 8;
    #pragma unroll
    for (int kk = 0; kk < 4; ++kk) {
        float4 u0 = *(const float4*)(xp + kk * 32);
        float4 u1 = *(const float4*)(xp + kk * 32 + 4);
        half8 af;
        af[0] = (_Float16)u0.x; af[1] = (_Float16)u0.y;
        af[2] = (_Float16)u0.z; af[3] = (_Float16)u0.w;
        af[4] = (_Float16)u1.x; af[5] = (_Float16)u1.y;
        af[6] = (_Float16)u1.z; af[7] = (_Float16)u1.w;
        #pragma unroll
        for (int n = 0; n < 4; ++n)
            acc[n] = __builtin_amdgcn_mfma_f32_16x16x32_f16(af, bf[kk][n], acc[n], 0, 0, 0);
    }
    int orow = wid * 16 + (l >> 4) * 4;
    int ocol = l & 15;
    #pragma unroll
    for (int n = 0; n < 4; ++n)
        #pragma unroll
        for (int r = 0; r < 4; ++r)
            h1h[(size_t)(orow + r) * HID + n * 16 + ocol] = __float2half(acc[n][r]);
}

// ---- E. bucket aggregation with in-LDS CSR.  MODE 0: relu(agg+b1)*mask -> hh
//                                              MODE 1: agg (incl self) -> agg_h
template<int MODE>
__global__ __launch_bounds__(256) void k_agg(const int* __restrict__ pairs,
                                             const int* __restrict__ bfill,
                                             const float* __restrict__ dinv,
                                             const __half* __restrict__ feat,
                                             const float* __restrict__ b1,
                                             const float* __restrict__ mask,
                                             __half* __restrict__ outp) {
    __shared__ int2 spw[CAP];            // {src, bits(dinv[src])}  20 KB
    __shared__ int ro[BNODES + 1];
    __shared__ int sc[BNODES];
    __shared__ int cnt2[BNODES];
    int b = blockIdx.x, t = threadIdx.x;
    if (t < BNODES) { sc[t] = 0; cnt2[t] = 0; }
    __syncthreads();
    int base = b * CAP, count = bfill[b];
    for (int i = t; i < count; i += 256)
        atomicAdd(&sc[pairs[base + i] & (BNODES - 1)], 1);
    __syncthreads();
    // inclusive scan over 128 entries
    for (int off = 1; off < BNODES; off <<= 1) {
        int u = (t >= off && t < BNODES) ? sc[t - off] : 0;
        __syncthreads();
        if (t < BNODES) sc[t] += u;
        __syncthreads();
    }
    if (t < BNODES) ro[t + 1] = sc[t];
    if (t == 0) ro[0] = 0;
    __syncthreads();
    // place edges sorted-by-dst in LDS, fetching dinv[src] along the way
    for (int i = t; i < count; i += 256) {
        int p  = pairs[base + i];
        int dl = p & (BNODES - 1);
        int s  = p >> BSH;
        int pos = ro[dl] + atomicAdd(&cnt2[dl], 1);
        spw[pos] = make_int2(s, __float_as_int(dinv[s]));
    }
    __syncthreads();
    // wave per node: register accumulate, unroll 8
    int wv = t >> 6, l = t & 63;
    int node0 = b << BSH;
    for (int n = wv; n < BNODES; n += 4) {
        int node = node0 + n;
        if (node >= NN) break;
        int beg = ro[n], end = ro[n + 1];
        float di = rsqrtf((float)(end - beg) + 1.0f);
        float acc = 0.f;
        int j = beg;
        for (; j + 8 <= end; j += 8) {
            int2 e0 = spw[j+0], e1 = spw[j+1], e2 = spw[j+2], e3 = spw[j+3];
            int2 e4 = spw[j+4], e5 = spw[j+5], e6 = spw[j+6], e7 = spw[j+7];
            float a0 = __half2float(feat[(size_t)e0.x * HID + l]);
            float a1 = __half2float(feat[(size_t)e1.x * HID + l]);
            float a2 = __half2float(feat[(size_t)e2.x * HID + l]);
            float a3 = __half2float(feat[(size_t)e3.x * HID + l]);
            float a4 = __half2float(feat[(size_t)e4.x * HID + l]);
            float a5 = __half2float(feat[(size_t)e5.x * HID + l]);
            float a6 = __half2float(feat[(size_t)e6.x * HID + l]);
            float a7 = __half2float(feat[(size_t)e7.x * HID + l]);
            acc = fmaf(a0, __int_as_float(e0.y), acc);
            acc = fmaf(a1, __int_as_float(e1.y), acc);
            acc = fmaf(a2, __int_as_float(e2.y), acc);
            acc = fmaf(a3, __int_as_float(e3.y), acc);
            acc = fmaf(a4, __int_as_float(e4.y), acc);
            acc = fmaf(a5, __int_as_float(e5.y), acc);
            acc = fmaf(a6, __int_as_float(e6.y), acc);
            acc = fmaf(a7, __int_as_float(e7.y), acc);
        }
        for (; j < end; ++j) {
            int2 e = spw[j];
            acc = fmaf(__half2float(feat[(size_t)e.x * HID + l]), __int_as_float(e.y), acc);
        }
        float selfv = __half2float(feat[(size_t)node * HID + l]);
        float v = acc * di + selfv * di * di;
        if (MODE == 0) {
            v += b1[l];
            v = v > 0.f ? v : 0.f;
            v *= mask[(size_t)node * HID + l];
        }
        outp[(size_t)node * HID + l] = __float2half(v);
    }
}

// ---- F. out = agg_h @ W2 + b2 (fp32) via MFMA: wave = 16 rows x 48(->40) ----
__global__ __launch_bounds__(256) void k_mgemm2(const _Float16* __restrict__ aggh,
                                                const _Float16* __restrict__ w2f,
                                                const float* __restrict__ b2,
                                                float* __restrict__ out) {
    int wid = (blockIdx.x * 256 + threadIdx.x) >> 6;
    int l = threadIdx.x & 63;
    if (wid >= NN / 16) return;
    half8 bf[2][3];
    #pragma unroll
    for (int kk = 0; kk < 2; ++kk)
        #pragma unroll
        for (int n = 0; n < 3; ++n)
            bf[kk][n] = ((const half8*)w2f)[(kk * 3 + n) * 64 + l];
    f32x4 acc[3] = {};
    int arow = wid * 16 + (l & 15);
    const _Float16* hp = aggh + (size_t)arow * HID + (l >> 4) * 8;
    #pragma unroll
    for (int kk = 0; kk < 2; ++kk) {
        half8 af = *(const half8*)(hp + kk * 32);
        #pragma unroll
        for (int n = 0; n < 3; ++n)
            acc[n] = __builtin_amdgcn_mfma_f32_16x16x32_f16(af, bf[kk][n], acc[n], 0, 0, 0);
    }
    int orow = wid * 16 + (l >> 4) * 4;
    int ocol = l & 15;
    #pragma unroll
    for (int n = 0; n < 3; ++n) {
        int col = n * 16 + ocol;
        if (col < OUTD) {
            float bb = b2[col];
            #pragma unroll
            for (int r = 0; r < 4; ++r)
                out[(size_t)(orow + r) * OUTD + col] = acc[n][r] + bb;
        }
    }
}

extern "C" void kernel_launch(void* const* d_in, const int* in_sizes, int n_in,
                              void* d_out, int out_size, void* d_ws, size_t ws_size,
                              hipStream_t stream) {
    const float* x    = (const float*)d_in[0];
    const int*   ei   = (const int*)d_in[1];
    const int*   src  = ei;
    const int*   dst  = ei + NE;
    const float* W1   = (const float*)d_in[2];
    const float* b1   = (const float*)d_in[3];
    const float* W2   = (const float*)d_in[4];
    const float* b2   = (const float*)d_in[5];
    const float* mask = (const float*)d_in[6];
    float* out = (float*)d_out;

    char* ws = (char*)d_ws;
    int*      bfill = (int*)ws;            ws += (size_t)NBKT * 4;
    float*    dinv  = (float*)ws;          ws += (size_t)NN * 4;
    _Float16* w1f   = (_Float16*)ws;       ws += 16 * 64 * 8 * 2;
    _Float16* w2f   = (_Float16*)ws;       ws += 6 * 64 * 8 * 2;
    int*      pairs = (int*)ws;            ws += (size_t)NBKT * CAP * 4;   // 8.0 MB
    __half*   h1h   = (__half*)ws;         ws += (size_t)NN * HID * 2;     // 12.8 MB
    __half*   hh    = (__half*)ws;         ws += (size_t)NN * HID * 2;     // 12.8 MB
    __half*   aggh  = h1h;                 // alias: h1h dead after k_agg<0>

    hipMemsetAsync(bfill, 0, (size_t)NBKT * 4, stream);

    k_pairs  <<<(NE + CCHUNK - 1) / CCHUNK, 256, 0, stream>>>(src, dst, bfill, pairs);
    k_degdinv<<<NBKT, 256, 0, stream>>>(pairs, bfill, dinv);
    k_wprep  <<<1, 256, 0, stream>>>(W1, W2, w1f, w2f);

    k_mgemm1 <<<(NN / 16 + 3) / 4, 256, 0, stream>>>(x, w1f, h1h);
    k_agg<0> <<<NBKT, 256, 0, stream>>>(pairs, bfill, dinv, h1h, b1, mask, hh);
    k_agg<1> <<<NBKT, 256, 0, stream>>>(pairs, bfill, dinv, hh, nullptr, nullptr, aggh);
    k_mgemm2 <<<(NN / 16 + 3) / 4, 256, 0, stream>>>((const _Float16*)aggh, w2f, b2, out);
}

// Round 8
// 204.944 us; speedup vs baseline: 1.2562x; 1.2562x over previous
//
#include <hip/hip_runtime.h>
#include <hip/hip_fp16.h>

#define NN     100000
#define NE     1600000
#define FEAT   128
#define HID    64
#define OUTD   40
#define BSH    8                         // bucket = dst >> 8 (256 nodes/bucket)
#define BNODES 256
#define NBKT   ((NN + BNODES - 1) / BNODES)   // 391
#define CAP    5120                      // bucket capacity (mean 4092, sd ~64)
#define CCHUNK 2048                      // edges per block (8 per thread)

typedef _Float16 half8 __attribute__((ext_vector_type(8)));
typedef float    f32x4 __attribute__((ext_vector_type(4)));

// ---- A. scatter packed (src<<8|dl) into bucket segments; offsets from LDS atomic returns ----
__global__ __launch_bounds__(256) void k_pairs(const int* __restrict__ src,
                                               const int* __restrict__ dst,
                                               int* __restrict__ bfill,
                                               int* __restrict__ pairs) {
    __shared__ int bcnt[NBKT];
    __shared__ int gb[NBKT];
    int t = threadIdx.x;
    for (int i = t; i < NBKT; i += 256) bcnt[i] = 0;
    __syncthreads();
    int e0 = blockIdx.x * CCHUNK;
    int pk[8], bb[8], off[8];
    #pragma unroll
    for (int i = 0; i < 8; ++i) {
        int e = e0 + i * 256 + t;
        if (e < NE) {
            int d = dst[e];
            pk[i]  = (src[e] << BSH) | (d & (BNODES - 1));
            bb[i]  = d >> BSH;
            off[i] = atomicAdd(&bcnt[bb[i]], 1);
        } else bb[i] = -1;
    }
    __syncthreads();
    for (int i = t; i < NBKT; i += 256) {
        int c = bcnt[i];
        gb[i] = c ? (i * CAP + atomicAdd(&bfill[i], c)) : 0;
    }
    __syncthreads();
    #pragma unroll
    for (int i = 0; i < 8; ++i)
        if (bb[i] >= 0) pairs[gb[bb[i]] + off[i]] = pk[i];
}

// ---- B. per-bucket degree hist -> global dinv ----
__global__ __launch_bounds__(256) void k_degdinv(const int* __restrict__ pairs,
                                                 const int* __restrict__ bfill,
                                                 float* __restrict__ dinv) {
    __shared__ int hist[BNODES];
    int b = blockIdx.x, t = threadIdx.x;
    hist[t] = 0;
    __syncthreads();
    int base = b * CAP, count = bfill[b];
    for (int i = t; i < count; i += 256)
        atomicAdd(&hist[pairs[base + i] & (BNODES - 1)], 1);
    __syncthreads();
    int node = (b << BSH) + t;
    if (node < NN) dinv[node] = rsqrtf((float)hist[t] + 1.0f);
}

// ---- C. per-bucket CSR with fused weights: csr = {src, bits(dinv[src]*dinv[dst])} ----
__global__ __launch_bounds__(256) void k_csr(const int* __restrict__ pairs,
                                             const int* __restrict__ bfill,
                                             const float* __restrict__ dinv,
                                             int* __restrict__ row_beg,
                                             int* __restrict__ row_end,
                                             int2* __restrict__ csr) {
    __shared__ int   nd[BNODES];
    __shared__ int   sc[BNODES];
    __shared__ int   ro[BNODES + 1];
    __shared__ int   cnt2[BNODES];
    __shared__ float ldin[BNODES];
    int b = blockIdx.x, t = threadIdx.x;
    nd[t] = 0; cnt2[t] = 0;
    __syncthreads();
    int base = b * CAP, count = bfill[b];
    for (int i = t; i < count; i += 256)
        atomicAdd(&nd[pairs[base + i] & (BNODES - 1)], 1);
    __syncthreads();
    int v = nd[t];
    ldin[t] = rsqrtf((float)v + 1.0f);
    sc[t] = v;
    __syncthreads();
    for (int off = 1; off < BNODES; off <<= 1) {
        int u = (t >= off) ? sc[t - off] : 0;
        __syncthreads();
        sc[t] += u;
        __syncthreads();
    }
    ro[t + 1] = sc[t];
    if (t == 0) ro[0] = 0;
    __syncthreads();
    int node = (b << BSH) + t;
    if (node < NN) {
        row_beg[node] = base + ro[t];
        row_end[node] = base + sc[t];
    }
    for (int i = t; i < count; i += 256) {
        int p  = pairs[base + i];
        int dl = p & (BNODES - 1);
        int s  = p >> BSH;
        int pos = ro[dl] + atomicAdd(&cnt2[dl], 1);
        csr[base + pos] = make_int2(s, __float_as_int(dinv[s] * ldin[dl]));
    }
}

// ---- D. pack W1/W2 into per-lane MFMA B-fragments (f16) ----
__global__ __launch_bounds__(256) void k_wprep(const float* __restrict__ W1,
                                               const float* __restrict__ W2,
                                               _Float16* __restrict__ w1f,
                                               _Float16* __restrict__ w2f) {
    int t = threadIdx.x;
    for (int it = t; it < 16 * 64; it += 256) {   // W1: kk 0..3 x n 0..3
        int f = it >> 6, l = it & 63;
        int kk = f >> 2, n = f & 3;
        int krow = kk * 32 + (l >> 4) * 8;
        int col  = n * 16 + (l & 15);
        #pragma unroll
        for (int i = 0; i < 8; ++i)
            w1f[it * 8 + i] = (_Float16)W1[(krow + i) * HID + col];
    }
    for (int it = t; it < 6 * 64; it += 256) {    // W2: kk 0..1 x n 0..2 (48-col pad)
        int f = it >> 6, l = it & 63;
        int kk = f / 3, n = f - kk * 3;
        int krow = kk * 32 + (l >> 4) * 8;
        int col  = n * 16 + (l & 15);
        #pragma unroll
        for (int i = 0; i < 8; ++i)
            w2f[it * 8 + i] = (col < OUTD) ? (_Float16)W2[(krow + i) * OUTD + col]
                                           : (_Float16)0.f;
    }
}

// ---- E. h1h = f16(x @ W1) via MFMA: wave = 16 rows x 64 cols ----
__global__ __launch_bounds__(256) void k_mgemm1(const float* __restrict__ x,
                                                const _Float16* __restrict__ w1f,
                                                __half* __restrict__ h1h) {
    int wid = (blockIdx.x * 256 + threadIdx.x) >> 6;
    int l = threadIdx.x & 63;
    if (wid >= NN / 16) return;
    half8 bf[4][4];
    #pragma unroll
    for (int kk = 0; kk < 4; ++kk)
        #pragma unroll
        for (int n = 0; n < 4; ++n)
            bf[kk][n] = ((const half8*)w1f)[(kk * 4 + n) * 64 + l];
    f32x4 acc[4] = {};
    int arow = wid * 16 + (l & 15);
    const float* xp = x + (size_t)arow * FEAT + (l >> 4) * 8;
    #pragma unroll
    for (int kk = 0; kk < 4; ++kk) {
        float4 u0 = *(const float4*)(xp + kk * 32);
        float4 u1 = *(const float4*)(xp + kk * 32 + 4);
        half8 af;
        af[0] = (_Float16)u0.x; af[1] = (_Float16)u0.y;
        af[2] = (_Float16)u0.z; af[3] = (_Float16)u0.w;
        af[4] = (_Float16)u1.x; af[5] = (_Float16)u1.y;
        af[6] = (_Float16)u1.z; af[7] = (_Float16)u1.w;
        #pragma unroll
        for (int n = 0; n < 4; ++n)
            acc[n] = __builtin_amdgcn_mfma_f32_16x16x32_f16(af, bf[kk][n], acc[n], 0, 0, 0);
    }
    int orow = wid * 16 + (l >> 4) * 4;
    int ocol = l & 15;
    #pragma unroll
    for (int n = 0; n < 4; ++n)
        #pragma unroll
        for (int r = 0; r < 4; ++r)
            h1h[(size_t)(orow + r) * HID + n * 16 + ocol] = __float2half(acc[n][r]);
}

// ---- F. conv1 aggregate: fp16 gathers, unroll-8 -> hh (f16) ----
__global__ __launch_bounds__(256) void k_agg1(const int* __restrict__ row_beg,
                                              const int* __restrict__ row_end,
                                              const int2* __restrict__ csr,
                                              const float* __restrict__ dinv,
                                              const __half* __restrict__ h1h,
                                              const float* __restrict__ b1,
                                              const float* __restrict__ mask,
                                              _Float16* __restrict__ hh) {
    int node = blockIdx.x * 4 + (threadIdx.x >> 6);
    if (node >= NN) return;
    int l = threadIdx.x & 63;
    int beg = __builtin_amdgcn_readfirstlane(row_beg[node]);
    int end = __builtin_amdgcn_readfirstlane(row_end[node]);
    float acc = 0.f;
    int j = beg;
    for (; j + 8 <= end; j += 8) {
        int2 e0 = csr[j+0], e1 = csr[j+1], e2 = csr[j+2], e3 = csr[j+3];
        int2 e4 = csr[j+4], e5 = csr[j+5], e6 = csr[j+6], e7 = csr[j+7];
        float a0 = __half2float(h1h[(size_t)e0.x * HID + l]);
        float a1 = __half2float(h1h[(size_t)e1.x * HID + l]);
        float a2 = __half2float(h1h[(size_t)e2.x * HID + l]);
        float a3 = __half2float(h1h[(size_t)e3.x * HID + l]);
        float a4 = __half2float(h1h[(size_t)e4.x * HID + l]);
        float a5 = __half2float(h1h[(size_t)e5.x * HID + l]);
        float a6 = __half2float(h1h[(size_t)e6.x * HID + l]);
        float a7 = __half2float(h1h[(size_t)e7.x * HID + l]);
        acc = fmaf(a0, __int_as_float(e0.y), acc);
        acc = fmaf(a1, __int_as_float(e1.y), acc);
        acc = fmaf(a2, __int_as_float(e2.y), acc);
        acc = fmaf(a3, __int_as_float(e3.y), acc);
        acc = fmaf(a4, __int_as_float(e4.y), acc);
        acc = fmaf(a5, __int_as_float(e5.y), acc);
        acc = fmaf(a6, __int_as_float(e6.y), acc);
        acc = fmaf(a7, __int_as_float(e7.y), acc);
    }
    for (; j < end; ++j) {
        int2 e = csr[j];
        acc = fmaf(__half2float(h1h[(size_t)e.x * HID + l]), __int_as_float(e.y), acc);
    }
    float di = dinv[node];
    float vv = acc + __half2float(h1h[(size_t)node * HID + l]) * di * di + b1[l];
    vv = vv > 0.f ? vv : 0.f;
    hh[(size_t)node * HID + l] = (_Float16)(vv * mask[(size_t)node * HID + l]);
}

// ---- G. h2h = f16(hh @ W2) via MFMA: wave = 16 rows x 48(->40) cols ----
__global__ __launch_bounds__(256) void k_mgemm2(const _Float16* __restrict__ hh,
                                                const _Float16* __restrict__ w2f,
                                                __half* __restrict__ h2h) {
    int wid = (blockIdx.x * 256 + threadIdx.x) >> 6;
    int l = threadIdx.x & 63;
    if (wid >= NN / 16) return;
    half8 bf[2][3];
    #pragma unroll
    for (int kk = 0; kk < 2; ++kk)
        #pragma unroll
        for (int n = 0; n < 3; ++n)
            bf[kk][n] = ((const half8*)w2f)[(kk * 3 + n) * 64 + l];
    f32x4 acc[3] = {};
    int arow = wid * 16 + (l & 15);
    const _Float16* hp = hh + (size_t)arow * HID + (l >> 4) * 8;
    #pragma unroll
    for (int kk = 0; kk < 2; ++kk) {
        half8 af = *(const half8*)(hp + kk * 32);
        #pragma unroll
        for (int n = 0; n < 3; ++n)
            acc[n] = __builtin_amdgcn_mfma_f32_16x16x32_f16(af, bf[kk][n], acc[n], 0, 0, 0);
    }
    int orow = wid * 16 + (l >> 4) * 4;
    int ocol = l & 15;
    #pragma unroll
    for (int n = 0; n < 3; ++n) {
        int col = n * 16 + ocol;
        if (col < OUTD) {
            #pragma unroll
            for (int r = 0; r < 4; ++r)
                h2h[(size_t)(orow + r) * OUTD + col] = __float2half(acc[n][r]);
        }
    }
}

// ---- H. conv2 aggregate: lanes >= OUTD exit; fp16 gathers, unroll-8 -> out ----
__global__ __launch_bounds__(256) void k_agg2(const int* __restrict__ row_beg,
                                              const int* __restrict__ row_end,
                                              const int2* __restrict__ csr,
                                              const float* __restrict__ dinv,
                                              const __half* __restrict__ h2h,
                                              const float* __restrict__ b2,
                                              float* __restrict__ out) {
    int node = blockIdx.x * 4 + (threadIdx.x >> 6);
    if (node >= NN) return;
    int l = threadIdx.x & 63;
    if (l >= OUTD) return;
    int beg = __builtin_amdgcn_readfirstlane(row_beg[node]);
    int end = __builtin_amdgcn_readfirstlane(row_end[node]);
    float acc = 0.f;
    int j = beg;
    for (; j + 8 <= end; j += 8) {
        int2 e0 = csr[j+0], e1 = csr[j+1], e2 = csr[j+2], e3 = csr[j+3];
        int2 e4 = csr[j+4], e5 = csr[j+5], e6 = csr[j+6], e7 = csr[j+7];
        float a0 = __half2float(h2h[(size_t)e0.x * OUTD + l]);
        float a1 = __half2float(h2h[(size_t)e1.x * OUTD + l]);
        float a2 = __half2float(h2h[(size_t)e2.x * OUTD + l]);
        float a3 = __half2float(h2h[(size_t)e3.x * OUTD + l]);
        float a4 = __half2float(h2h[(size_t)e4.x * OUTD + l]);
        float a5 = __half2float(h2h[(size_t)e5.x * OUTD + l]);
        float a6 = __half2float(h2h[(size_t)e6.x * OUTD + l]);
        float a7 = __half2float(h2h[(size_t)e7.x * OUTD + l]);
        acc = fmaf(a0, __int_as_float(e0.y), acc);
        acc = fmaf(a1, __int_as_float(e1.y), acc);
        acc = fmaf(a2, __int_as_float(e2.y), acc);
        acc = fmaf(a3, __int_as_float(e3.y), acc);
        acc = fmaf(a4, __int_as_float(e4.y), acc);
        acc = fmaf(a5, __int_as_float(e5.y), acc);
        acc = fmaf(a6, __int_as_float(e6.y), acc);
        acc = fmaf(a7, __int_as_float(e7.y), acc);
    }
    for (; j < end; ++j) {
        int2 e = csr[j];
        acc = fmaf(__half2float(h2h[(size_t)e.x * OUTD + l]), __int_as_float(e.y), acc);
    }
    float di = dinv[node];
    out[(size_t)node * OUTD + l] = acc + __half2float(h2h[(size_t)node * OUTD + l]) * di * di + b2[l];
}

extern "C" void kernel_launch(void* const* d_in, const int* in_sizes, int n_in,
                              void* d_out, int out_size, void* d_ws, size_t ws_size,
                              hipStream_t stream) {
    const float* x    = (const float*)d_in[0];
    const int*   ei   = (const int*)d_in[1];
    const int*   src  = ei;
    const int*   dst  = ei + NE;
    const float* W1   = (const float*)d_in[2];
    const float* b1   = (const float*)d_in[3];
    const float* W2   = (const float*)d_in[4];
    const float* b2   = (const float*)d_in[5];
    const float* mask = (const float*)d_in[6];
    float* out = (float*)d_out;

    char* ws = (char*)d_ws;
    int*      bfill   = (int*)ws;          ws += (size_t)NBKT * 4;
    int*      row_beg = (int*)ws;          ws += (size_t)NN * 4;
    int*      row_end = (int*)ws;          ws += (size_t)NN * 4;
    float*    dinv    = (float*)ws;        ws += (size_t)NN * 4;
    _Float16* w1f     = (_Float16*)ws;     ws += 16 * 64 * 8 * 2;
    _Float16* w2f     = (_Float16*)ws;     ws += 6 * 64 * 8 * 2;
    int2*     csr     = (int2*)ws;         ws += (size_t)NBKT * CAP * 8;   // 16.0 MB
    __half*   h1h     = (__half*)ws;       ws += (size_t)NN * HID * 2;     // 12.8 MB
    _Float16* hh      = (_Float16*)ws;     ws += (size_t)NN * HID * 2;     // 12.8 MB
    int*      pairs   = (int*)hh;          // alias: pairs (8 MB) dead before hh written
    __half*   h2h     = h1h;               // alias: h1h dead after k_agg1

    hipMemsetAsync(bfill, 0, (size_t)NBKT * 4, stream);

    k_pairs  <<<(NE + CCHUNK - 1) / CCHUNK, 256, 0, stream>>>(src, dst, bfill, pairs);
    k_degdinv<<<NBKT, 256, 0, stream>>>(pairs, bfill, dinv);
    k_csr    <<<NBKT, 256, 0, stream>>>(pairs, bfill, dinv, row_beg, row_end, csr);
    k_wprep  <<<1, 256, 0, stream>>>(W1, W2, w1f, w2f);

    k_mgemm1 <<<(NN / 16 + 3) / 4, 256, 0, stream>>>(x, w1f, h1h);
    k_agg1   <<<(NN + 3) / 4, 256, 0, stream>>>(row_beg, row_end, csr, dinv,
                                                h1h, b1, mask, hh);
    k_mgemm2 <<<(NN / 16 + 3) / 4, 256, 0, stream>>>(hh, w2f, h2h);
    k_agg2   <<<(NN + 3) / 4, 256, 0, stream>>>(row_beg, row_end, csr, dinv,
                                                h2h, b2, out);
}